// Round 3
// baseline (300.327 us; speedup 1.0000x reference)
//
#include <hip/hip_runtime.h>
#include <stdint.h>

typedef unsigned long long u64;
typedef unsigned int u32;

#define N_MASKS 1536
#define HW 50176           // 224*224
#define WORDS 784          // 12*64 + 16
#define NCLS 80
#define POST_NMS_K 768
#define SEG_ELEMS ((size_t)POST_NMS_K * HW)   // 38,535,168
#define KEYPAD 2048
#define BITS_BYTES ((size_t)N_MASKS * WORDS * 8)   // 9,633,792

// ---------------- Kernel 1: bitpack via wave ballot ----------------
// Wave packs 256 consecutive pixels: lane reads float4, 4 ballots -> 4 u64.
// Fixed pixel->bit permutation, identical across masks: popcount(a&b) exact.
__global__ __launch_bounds__(256) void pack_kernel(const float4* __restrict__ masks,
                                                   u64* __restrict__ bits) {
    int gid = blockIdx.x * blockDim.x + threadIdx.x;
    int wave = gid >> 6;
    int lane = gid & 63;
    float4 v = masks[(size_t)wave * 64 + lane];
    u64 b0 = __ballot(v.x > 0.5f);
    u64 b1 = __ballot(v.y > 0.5f);
    u64 b2 = __ballot(v.z > 0.5f);
    u64 b3 = __ballot(v.w > 0.5f);
    if (lane < 4) {
        u64 w = (lane == 0) ? b0 : (lane == 1) ? b1 : (lane == 2) ? b2 : b3;
        bits[(size_t)wave * 4 + lane] = w;
    }
}

// ---------------- Kernel 2: setup — member lists, ranks, pair offsets ------
__global__ __launch_bounds__(256) void setup_kernel(
        const int* __restrict__ labels,
        int* __restrict__ members, int* __restrict__ classBase,
        int* __restrict__ pairOff, int* __restrict__ rank) {
    __shared__ int lab[N_MASKS];
    __shared__ int cnt[NCLS];
    __shared__ int base[NCLS + 1];
    const int tid = threadIdx.x;
    for (int i = tid; i < N_MASKS; i += 256) lab[i] = labels[i];
    __syncthreads();
    if (tid < NCLS) {
        int c = 0;
        for (int i = 0; i < N_MASKS; ++i) c += (lab[i] == tid);
        cnt[tid] = c;
    }
    __syncthreads();
    if (tid == 0) {
        int s = 0, ps = 0;
        for (int c = 0; c < NCLS; ++c) {
            base[c] = s; classBase[c] = s;
            pairOff[c] = ps;
            int m = cnt[c];
            s += m; ps += m * (m - 1) / 2;
        }
        base[NCLS] = s; classBase[NCLS] = s; pairOff[NCLS] = ps;
    }
    __syncthreads();
    if (tid < NCLS) {
        int o = base[tid];
        for (int i = 0; i < N_MASKS; ++i)
            if (lab[i] == tid) { rank[i] = o - base[tid]; members[o++] = i; }
    }
}

// Load one bit-row into 13 u64 registers (static indices -> stays in VGPRs;
// 24+2 loads issued back-to-back = full memory-level parallelism).
#define LOADROW(dst, row)                                           \
    {                                                               \
        const u64* _r = (row);                                      \
        _Pragma("unroll")                                           \
        for (int _t = 0; _t < 12; ++_t) dst[_t] = _r[lane + _t*64]; \
        dst[12] = (lane < 16) ? _r[768 + lane] : 0ull;              \
    }

// ---------------- Kernel 3: one wave per column — D row + compensate -------
// D[a][b] = I/(2*S_b - I + eps)   (reference quirk: union = 2*S_col - I)
// Wave owns column b: comp[b] = max_a D  -> plain store, no atomics.
// Dp slice for column b is contiguous: pairOff[c] + b(b-1)/2 + a.
__global__ __launch_bounds__(256) void pairsD_kernel(
        const int* __restrict__ labels, const int* __restrict__ rank,
        const int* __restrict__ members, const int* __restrict__ classBase,
        const int* __restrict__ pairOff, const float* __restrict__ msum,
        const u64* __restrict__ bits, float* __restrict__ Dp,
        float* __restrict__ comp) {
    const int lane = threadIdx.x & 63;
    const int wid = blockIdx.x * (blockDim.x >> 6) + (threadIdx.x >> 6);
    if (wid >= N_MASKS) return;
    const int g = wid;
    const int c = labels[g];
    const int b = rank[g];
    const int cb = classBase[c];
    const int pairbase = pairOff[c] + b * (b - 1) / 2;
    const float Sb2 = 2.0f * msum[g];

    u64 rb[13], cur[13], nxt[13];
    LOADROW(rb, bits + (size_t)g * WORDS);
    float cmax = 0.0f;
    if (b > 0) {
        LOADROW(cur, bits + (size_t)members[cb] * WORDS);
        for (int a = 0; a < b; ++a) {
            if (a + 1 < b) LOADROW(nxt, bits + (size_t)members[cb + a + 1] * WORDS);
            int I = 0;
#pragma unroll
            for (int t = 0; t < 13; ++t) I += (int)__popcll(cur[t] & rb[t]);
#pragma unroll
            for (int off = 32; off; off >>= 1) I += __shfl_xor(I, off, 64);
            float fI = (float)I;
            float D = fI / (Sb2 - fI + 1e-6f);      // D in [0,1]
            cmax = fmaxf(cmax, D);
            if (lane == 0) Dp[pairbase + a] = D;
            if (a + 1 < b) {
#pragma unroll
                for (int t = 0; t < 13; ++t) cur[t] = nxt[t];
            }
        }
    }
    if (lane == 0) comp[g] = cmax;
}

// ---------------- Kernel 4: per-column M + keys + bitonic top-k ------------
// M[b] = max(0, max_{a<b}(D_ab^2 - comp[a]^2)); decay = exp(-M/0.5).
// (min over non-pred rows of exp(+2*comp^2) is >=1 and row with comp=0 always
//  exists, so the clamp at 0 is faithful to the reference.)
__global__ __launch_bounds__(1024) void sortM_kernel(
        const int* __restrict__ labels, const int* __restrict__ rank,
        const int* __restrict__ members, const int* __restrict__ classBase,
        const int* __restrict__ pairOff, const float* __restrict__ Dp,
        const float* __restrict__ comp, const float* __restrict__ scores,
        const float* __restrict__ factors,
        int* __restrict__ sel, float* __restrict__ out_small) {
    __shared__ u64 k2[KEYPAD];
    const int tid = threadIdx.x;
    for (int i = tid; i < KEYPAD; i += 1024) {
        u64 v = 0;
        if (i < N_MASKS) {
            int c = labels[i];
            int b = rank[i];
            int cb = classBase[c];
            int pb = pairOff[c] + b * (b - 1) / 2;
            float m = 0.0f;
            for (int a = 0; a < b; ++a) {
                float D = Dp[pb + a];
                float ca = comp[members[cb + a]];
                m = fmaxf(m, D * D - ca * ca);
            }
            float sc = scores[i];
            float key = (sc * __expf(-2.0f * m) >= 0.5f) ? sc : -1.0f;
            u32 fb = __float_as_uint(key);
            u32 od = (fb & 0x80000000u) ? ~fb : (fb | 0x80000000u);  // order-keep
            v = ((u64)od << 32) | (u32)(~(u32)i);                    // tie->low idx
        }
        k2[i] = v;
    }
    __syncthreads();
    for (int k = 2; k <= KEYPAD; k <<= 1) {
        for (int j = k >> 1; j > 0; j >>= 1) {
            for (int i = tid; i < KEYPAD; i += 1024) {
                int p = i ^ j;
                if (p > i) {
                    bool desc = ((i & k) == 0);
                    u64 x = k2[i], y = k2[p];
                    if ((x < y) == desc) { k2[i] = y; k2[p] = x; }
                }
            }
            __syncthreads();
        }
    }
    for (int r = tid; r < POST_NMS_K; r += 1024) {
        u64 v = k2[r];
        u32 od = (u32)(v >> 32);
        bool kept = (od >= 0x80000000u);    // key float >= 0 (pads have od==0)
        int idx = (int)(~(u32)v);
        if (kept) {
            sel[r] = idx;
            out_small[r] = scores[idx];
            out_small[POST_NMS_K + r] = (float)labels[idx];
            out_small[2 * POST_NMS_K + r] = factors[idx];
        } else {
            sel[r] = -1;
            out_small[r] = 0.0f;
            out_small[POST_NMS_K + r] = -1.0f;
            out_small[2 * POST_NMS_K + r] = 0.0f;
        }
    }
}

// ---------------- Kernel 5: gather seg rows ----------------
__global__ __launch_bounds__(256) void gather_kernel(const float4* __restrict__ seg,
                                                     const int* __restrict__ sel,
                                                     float4* __restrict__ out) {
    int row = blockIdx.y;
    int col = blockIdx.x * blockDim.x + threadIdx.x;   // 0..12543
    int s = sel[row];
    float4 v = make_float4(0.f, 0.f, 0.f, 0.f);
    if (s >= 0) v = seg[(size_t)s * (HW / 4) + col];
    out[(size_t)row * (HW / 4) + col] = v;
}

extern "C" void kernel_launch(void* const* d_in, const int* in_sizes, int n_in,
                              void* d_out, int out_size, void* d_ws, size_t ws_size,
                              hipStream_t stream) {
    const int* labels = (const int*)d_in[0];
    const float* scores = (const float*)d_in[1];
    const float* factors = (const float*)d_in[2];
    const float* seg = (const float*)d_in[3];
    const float* masks = (const float*)d_in[4];
    const float* msum = (const float*)d_in[5];

    float* out = (float*)d_out;
    // Scratch in d_out's seg region (overwritten by gather at the very end):
    //   [0, 9.6MB)  packed bits ;  [9.6MB, +4.7MB) per-pair D values
    u64* bits = (u64*)d_out;
    float* Dp = (float*)((char*)d_out + BITS_BYTES);

    // d_ws: members[1536] classBase[81] pairOff[81] rank[1536] comp[1536]
    //       sel[768]   (~22 KB)
    int* members = (int*)d_ws;
    int* classBase = members + N_MASKS;
    int* pairOff = classBase + (NCLS + 1);
    int* rank = pairOff + (NCLS + 1);
    float* comp = (float*)(rank + N_MASKS);
    int* sel = (int*)(comp + N_MASKS);

    {   // pack: 1536 masks * 196 wave-groups of 256 px; 4 waves/block
        int groups = N_MASKS * (HW / 256);
        pack_kernel<<<groups / 4, 256, 0, stream>>>((const float4*)masks, bits);
    }
    setup_kernel<<<1, 256, 0, stream>>>(labels, members, classBase, pairOff, rank);
    // one wave per column: 1536 waves = 384 blocks x 4 waves
    pairsD_kernel<<<N_MASKS / 4, 256, 0, stream>>>(labels, rank, members,
                                                   classBase, pairOff, msum,
                                                   bits, Dp, comp);
    sortM_kernel<<<1, 1024, 0, stream>>>(labels, rank, members, classBase,
                                         pairOff, Dp, comp, scores, factors,
                                         sel, out + SEG_ELEMS);
    {   // gather: 12544 float4 per row; 49 blocks x 256 threads
        dim3 grid(49, POST_NMS_K);
        gather_kernel<<<grid, 256, 0, stream>>>((const float4*)seg, sel,
                                                (float4*)out);
    }
}

// Round 4
// 274.722 us; speedup vs baseline: 1.0932x; 1.0932x over previous
//
#include <hip/hip_runtime.h>
#include <stdint.h>

typedef unsigned long long u64;
typedef unsigned int u32;

#define N_MASKS 1536
#define HW 50176           // 224*224
#define WORDS 784          // 12*64 + 16
#define NCLS 80
#define POST_NMS_K 768
#define SEG_ELEMS ((size_t)POST_NMS_K * HW)   // 38,535,168
#define KEYPAD 2048
#define BITS_BYTES ((size_t)N_MASKS * WORDS * 8)   // 9,633,792
#define NCHUNK (N_MASKS / 64)                       // 24

// ---------------- Kernel 1: bitpack via wave ballot ----------------
// Wave packs 256 consecutive pixels: lane reads float4, 4 ballots -> 4 u64.
// Fixed pixel->bit permutation, identical across masks: popcount(a&b) exact.
__global__ __launch_bounds__(256) void pack_kernel(const float4* __restrict__ masks,
                                                   u64* __restrict__ bits) {
    int gid = blockIdx.x * blockDim.x + threadIdx.x;
    int wave = gid >> 6;
    int lane = gid & 63;
    float4 v = masks[(size_t)wave * 64 + lane];
    u64 b0 = __ballot(v.x > 0.5f);
    u64 b1 = __ballot(v.y > 0.5f);
    u64 b2 = __ballot(v.z > 0.5f);
    u64 b3 = __ballot(v.w > 0.5f);
    if (lane < 4) {
        u64 w = (lane == 0) ? b0 : (lane == 1) ? b1 : (lane == 2) ? b2 : b3;
        bits[(size_t)wave * 4 + lane] = w;
    }
}

// ---------------- Kernel 2: setup — wave-parallel stable counting sort -----
// One wave. 24 chunks of 64 labels; intra-chunk stable rank via 64-step
// shuffle compare (VALU, no LDS latency chains); running class counters in
// LDS advanced by the unique last-lane-of-label per chunk.
__global__ __launch_bounds__(64) void setup_kernel(
        const int* __restrict__ labels,
        int* __restrict__ members, int* __restrict__ classBase,
        int* __restrict__ pairOff, int* __restrict__ rank) {
    __shared__ int cnt[NCLS];
    __shared__ int labS[N_MASKS];
    __shared__ int rnkS[N_MASKS];
    __shared__ int base[NCLS + 1];
    __shared__ int poff[NCLS + 1];
    const int lane = threadIdx.x;
    for (int c = lane; c < NCLS; c += 64) cnt[c] = 0;
    for (int ch = 0; ch < NCHUNK; ++ch) labS[ch * 64 + lane] = labels[ch * 64 + lane];
    __syncthreads();
    for (int ch = 0; ch < NCHUNK; ++ch) {
        int myLab = labS[ch * 64 + lane];
        int myrank = 0, later = 0;
#pragma unroll
        for (int s = 0; s < 64; ++s) {
            int ol = __shfl(myLab, s);
            if (ol == myLab) { if (s < lane) ++myrank; else if (s > lane) ++later; }
        }
        int basec = cnt[myLab];                    // wave-lockstep: read then write
        rnkS[ch * 64 + lane] = basec + myrank;
        if (later == 0) cnt[myLab] = basec + myrank + 1;   // unique lane per label
        __syncthreads();
    }
    if (lane == 0) {
        int s = 0, ps = 0;
        for (int c = 0; c < NCLS; ++c) {
            base[c] = s; poff[c] = ps;
            int m = cnt[c];
            s += m; ps += m * (m - 1) / 2;
        }
        base[NCLS] = s; poff[NCLS] = ps;
    }
    __syncthreads();
    for (int c = lane; c <= NCLS; c += 64) { classBase[c] = base[c]; pairOff[c] = poff[c]; }
    for (int ch = 0; ch < NCHUNK; ++ch) {
        int i = ch * 64 + lane;
        int r = rnkS[i];
        int c = labS[i];
        rank[i] = r;
        members[base[c] + r] = i;
    }
}

// Load one bit-row into 13 u64 registers (static indices -> stays in VGPRs;
// 26 loads issued back-to-back = full memory-level parallelism).
#define LOADROW(dst, row)                                           \
    {                                                               \
        const u64* _r = (row);                                      \
        _Pragma("unroll")                                           \
        for (int _t = 0; _t < 12; ++_t) dst[_t] = _r[lane + _t*64]; \
        dst[12] = (lane < 16) ? _r[768 + lane] : 0ull;              \
    }

// ---------------- Kernel 3: one wave per column — D row + compensate -------
// D[a][b] = I/(2*S_b - I + eps)   (reference quirk: union = 2*S_col - I)
// Wave owns column b: compM[slot b] = max_a D -> plain store, no atomics.
// Dp slice for column b is contiguous: pairOff[c] + b(b-1)/2 + a.
__global__ __launch_bounds__(256) void pairsD_kernel(
        const int* __restrict__ labels, const int* __restrict__ rank,
        const int* __restrict__ members, const int* __restrict__ classBase,
        const int* __restrict__ pairOff, const float* __restrict__ msum,
        const u64* __restrict__ bits, float* __restrict__ Dp,
        float* __restrict__ compM) {
    const int lane = threadIdx.x & 63;
    const int wid = blockIdx.x * (blockDim.x >> 6) + (threadIdx.x >> 6);
    if (wid >= N_MASKS) return;
    const int g = wid;
    const int c = labels[g];
    const int b = rank[g];
    const int cb = classBase[c];
    const int pairbase = pairOff[c] + b * (b - 1) / 2;
    const float Sb2 = 2.0f * msum[g];

    u64 rb[13], cur[13], nxt[13];
    LOADROW(rb, bits + (size_t)g * WORDS);
    float cmax = 0.0f;
    if (b > 0) {
        LOADROW(cur, bits + (size_t)members[cb] * WORDS);
        for (int a = 0; a < b; ++a) {
            if (a + 1 < b) LOADROW(nxt, bits + (size_t)members[cb + a + 1] * WORDS);
            int I = 0;
#pragma unroll
            for (int t = 0; t < 13; ++t) I += (int)__popcll(cur[t] & rb[t]);
#pragma unroll
            for (int off = 32; off; off >>= 1) I += __shfl_xor(I, off, 64);
            float fI = (float)I;
            float D = fI / (Sb2 - fI + 1e-6f);      // D in [0,1]
            cmax = fmaxf(cmax, D);
            if (lane == 0) Dp[pairbase + a] = D;
            if (a + 1 < b) {
#pragma unroll
                for (int t = 0; t < 13; ++t) cur[t] = nxt[t];
            }
        }
    }
    if (lane == 0) compM[cb + b] = cmax;           // indexed by member slot
}

// ---------------- Kernel 4: per-column M + keys + bitonic top-k ------------
// M[b] = max(0, max_{a<b}(D_ab^2 - compM[a]^2)); decay = exp(-M/0.5).
// (A row with comp=0, d=0 always exists, so the 0-clamp is faithful.)
__global__ __launch_bounds__(1024) void sortM_kernel(
        const int* __restrict__ labels, const int* __restrict__ rank,
        const int* __restrict__ classBase, const int* __restrict__ pairOff,
        const float* __restrict__ Dp, const float* __restrict__ compM,
        const float* __restrict__ scores, const float* __restrict__ factors,
        int* __restrict__ sel, float* __restrict__ out_small) {
    __shared__ u64 k2[KEYPAD];
    const int tid = threadIdx.x;
    for (int i = tid; i < KEYPAD; i += 1024) {
        u64 v = 0;
        if (i < N_MASKS) {
            int c = labels[i];
            int b = rank[i];
            int cb = classBase[c];
            int pb = pairOff[c] + b * (b - 1) / 2;
            float m = 0.0f;
            for (int a = 0; a < b; ++a) {
                float D = Dp[pb + a];
                float ca = compM[cb + a];           // contiguous now
                m = fmaxf(m, D * D - ca * ca);
            }
            float sc = scores[i];
            float key = (sc * __expf(-2.0f * m) >= 0.5f) ? sc : -1.0f;
            u32 fb = __float_as_uint(key);
            u32 od = (fb & 0x80000000u) ? ~fb : (fb | 0x80000000u);  // order-keep
            v = ((u64)od << 32) | (u32)(~(u32)i);                    // tie->low idx
        }
        k2[i] = v;
    }
    __syncthreads();
    for (int k = 2; k <= KEYPAD; k <<= 1) {
        for (int j = k >> 1; j > 0; j >>= 1) {
            for (int i = tid; i < KEYPAD; i += 1024) {
                int p = i ^ j;
                if (p > i) {
                    bool desc = ((i & k) == 0);
                    u64 x = k2[i], y = k2[p];
                    if ((x < y) == desc) { k2[i] = y; k2[p] = x; }
                }
            }
            __syncthreads();
        }
    }
    for (int r = tid; r < POST_NMS_K; r += 1024) {
        u64 v = k2[r];
        u32 od = (u32)(v >> 32);
        bool kept = (od >= 0x80000000u);    // key float >= 0 (pads have od==0)
        int idx = (int)(~(u32)v);
        if (kept) {
            sel[r] = idx;
            out_small[r] = scores[idx];
            out_small[POST_NMS_K + r] = (float)labels[idx];
            out_small[2 * POST_NMS_K + r] = factors[idx];
        } else {
            sel[r] = -1;
            out_small[r] = 0.0f;
            out_small[POST_NMS_K + r] = -1.0f;
            out_small[2 * POST_NMS_K + r] = 0.0f;
        }
    }
}

// ---------------- Kernel 5: gather seg rows ----------------
__global__ __launch_bounds__(256) void gather_kernel(const float4* __restrict__ seg,
                                                     const int* __restrict__ sel,
                                                     float4* __restrict__ out) {
    int row = blockIdx.y;
    int col = blockIdx.x * blockDim.x + threadIdx.x;   // 0..12543
    int s = sel[row];
    float4 v = make_float4(0.f, 0.f, 0.f, 0.f);
    if (s >= 0) v = seg[(size_t)s * (HW / 4) + col];
    out[(size_t)row * (HW / 4) + col] = v;
}

extern "C" void kernel_launch(void* const* d_in, const int* in_sizes, int n_in,
                              void* d_out, int out_size, void* d_ws, size_t ws_size,
                              hipStream_t stream) {
    const int* labels = (const int*)d_in[0];
    const float* scores = (const float*)d_in[1];
    const float* factors = (const float*)d_in[2];
    const float* seg = (const float*)d_in[3];
    const float* masks = (const float*)d_in[4];
    const float* msum = (const float*)d_in[5];

    float* out = (float*)d_out;
    // Scratch in d_out's seg region (overwritten by gather at the very end):
    //   [0, 9.6MB)  packed bits ;  [9.6MB, +4.7MB) per-pair D values
    u64* bits = (u64*)d_out;
    float* Dp = (float*)((char*)d_out + BITS_BYTES);

    // d_ws: members[1536] classBase[81] pairOff[81] rank[1536] compM[1536]
    //       sel[768]   (~22 KB)
    int* members = (int*)d_ws;
    int* classBase = members + N_MASKS;
    int* pairOff = classBase + (NCLS + 1);
    int* rank = pairOff + (NCLS + 1);
    float* compM = (float*)(rank + N_MASKS);
    int* sel = (int*)(compM + N_MASKS);

    {   // pack: 1536 masks * 196 wave-groups of 256 px; 4 waves/block
        int groups = N_MASKS * (HW / 256);
        pack_kernel<<<groups / 4, 256, 0, stream>>>((const float4*)masks, bits);
    }
    setup_kernel<<<1, 64, 0, stream>>>(labels, members, classBase, pairOff, rank);
    // one wave per column: 1536 waves = 384 blocks x 4 waves
    pairsD_kernel<<<N_MASKS / 4, 256, 0, stream>>>(labels, rank, members,
                                                   classBase, pairOff, msum,
                                                   bits, Dp, compM);
    sortM_kernel<<<1, 1024, 0, stream>>>(labels, rank, classBase, pairOff,
                                         Dp, compM, scores, factors,
                                         sel, out + SEG_ELEMS);
    {   // gather: 12544 float4 per row; 49 blocks x 256 threads
        dim3 grid(49, POST_NMS_K);
        gather_kernel<<<grid, 256, 0, stream>>>((const float4*)seg, sel,
                                                (float4*)out);
    }
}

// Round 5
// 202.150 us; speedup vs baseline: 1.4857x; 1.3590x over previous
//
#include <hip/hip_runtime.h>
#include <stdint.h>

typedef unsigned long long u64;
typedef unsigned int u32;
typedef unsigned short u16;

#define N_MASKS 1536
#define HW 50176           // 224*224
#define WORDS 784
#define NCLS 80
#define POST_NMS_K 768
#define SEG_ELEMS ((size_t)POST_NMS_K * HW)   // 38,535,168
#define KEYPAD 2048
#define BITS_BYTES ((size_t)N_MASKS * WORDS * 8)   // 9,633,792

#define MMAX 96                       // max members/class (binomial max ~45; 96 = huge margin)
#define MAXPAIRS (MMAX*(MMAX-1)/2)    // 4560
#define TW 112                        // words per LDS tile; 784 = 7*112
#define TWP 113                       // padded stride: breaks 32-bank alignment
#define NTILES (WORDS/TW)             // 7

// ---------------- Kernel 1: bitpack via wave ballot ----------------
__global__ __launch_bounds__(256) void pack_kernel(const float4* __restrict__ masks,
                                                   u64* __restrict__ bits) {
    int gid = blockIdx.x * blockDim.x + threadIdx.x;
    int wave = gid >> 6;
    int lane = gid & 63;
    float4 v = masks[(size_t)wave * 64 + lane];
    u64 b0 = __ballot(v.x > 0.5f);
    u64 b1 = __ballot(v.y > 0.5f);
    u64 b2 = __ballot(v.z > 0.5f);
    u64 b3 = __ballot(v.w > 0.5f);
    if (lane < 4) {
        u64 w = (lane == 0) ? b0 : (lane == 1) ? b1 : (lane == 2) ? b2 : b3;
        bits[(size_t)wave * 4 + lane] = w;
    }
}

// ---------------- Kernel 2: fused per-class matrix NMS ----------------
// One block per class. All pair intersections computed from LDS-staged bit
// tiles (no global latency in inner loop, no cross-lane reduces), then
// D -> compensate -> M -> keys entirely in LDS.
// D[a][b] = I/(2*S_b - I + eps)   (reference quirk: union = 2*S_col - I)
// M[b] = max(0, max_{a<b}(D^2 - comp[a]^2));  key = (sc*exp(-2M) >= 0.5) ? sc : -1
__global__ __launch_bounds__(256) void classnms_kernel(
        const int* __restrict__ labels, const float* __restrict__ scores,
        const float* __restrict__ msum, const u64* __restrict__ bits,
        float* __restrict__ keys) {
    const int cls = blockIdx.x;
    const int tid = threadIdx.x;
    __shared__ int mem[MMAX];
    __shared__ float Sm[MMAX], Sc[MMAX];
    __shared__ u32 compS[MMAX], Ms[MMAX];
    __shared__ u16 lutAB[MAXPAIRS];          // (a<<8)|b
    __shared__ u32 Ipair[MAXPAIRS];          // intersections, then D bits
    __shared__ u64 rows[MMAX * TWP];         // 96*113*8 = 86.6 KB
    __shared__ int scan[256];
    __shared__ int mtot;

    // --- ordered compaction: thread t owns indices [6t, 6t+6) ---
    const int PER = N_MASKS / 256;           // 6
    int lab[PER]; int cnt = 0;
#pragma unroll
    for (int k = 0; k < PER; ++k) { lab[k] = labels[tid * PER + k]; cnt += (lab[k] == cls); }
    scan[tid] = cnt;
    __syncthreads();
    for (int off = 1; off < 256; off <<= 1) {   // Hillis-Steele inclusive scan
        int v = scan[tid];
        int u = (tid >= off) ? scan[tid - off] : 0;
        __syncthreads();
        scan[tid] = v + u;
        __syncthreads();
    }
    {
        int o = scan[tid] - cnt;             // exclusive offset
#pragma unroll
        for (int k = 0; k < PER; ++k)
            if (lab[k] == cls) mem[o++] = tid * PER + k;
    }
    if (tid == 255) mtot = scan[255];
    __syncthreads();
    const int m = mtot;                      // ~19 avg, <96 guaranteed
    const int np = m * (m - 1) / 2;

    for (int b = tid; b < m; b += 256) {
        int g = mem[b];
        Sm[b] = msum[g]; Sc[b] = scores[g];
        compS[b] = 0u; Ms[b] = 0u;
    }
    for (int p = tid; p < np; p += 256) {    // pair LUT (decode once)
        int bb = (int)((1.0 + sqrt(1.0 + 8.0 * (double)p)) * 0.5);
        while (bb * (bb - 1) / 2 > p) --bb;
        while ((bb + 1) * bb / 2 <= p) ++bb;
        int aa = p - bb * (bb - 1) / 2;
        lutAB[p] = (u16)((aa << 8) | bb);
        Ipair[p] = 0u;
    }

    // --- tiled pairwise popcount from LDS ---
    for (int t = 0; t < NTILES; ++t) {
        __syncthreads();
        for (int idx = tid; idx < m * TW; idx += 256) {
            int r = idx / TW, w = idx - r * TW;
            rows[r * TWP + w] = bits[(size_t)mem[r] * WORDS + t * TW + w];
        }
        __syncthreads();
        for (int p = tid; p < np; p += 256) {
            int ab = lutAB[p];
            const u64* ra = &rows[(ab >> 8) * TWP];
            const u64* rb = &rows[(ab & 255) * TWP];
            u32 s = 0;
#pragma unroll 8
            for (int w = 0; w < TW; ++w) s += (u32)__popcll(ra[w] & rb[w]);
            Ipair[p] += s;                   // thread owns p: plain add
        }
    }
    __syncthreads();

    // --- D + compensate ---
    for (int p = tid; p < np; p += 256) {
        int ab = lutAB[p]; int bcol = ab & 255;
        float fI = (float)Ipair[p];
        float D = fI / (2.0f * Sm[bcol] - fI + 1e-6f);   // D in [0,1]
        Ipair[p] = __float_as_uint(D);       // same-thread overwrite: safe
        atomicMax(&compS[bcol], __float_as_uint(D));     // non-neg: uint==float order
    }
    __syncthreads();
    // --- M ---
    for (int p = tid; p < np; p += 256) {
        int ab = lutAB[p]; int aa = ab >> 8; int bcol = ab & 255;
        float D = __uint_as_float(Ipair[p]);
        float ca = __uint_as_float(compS[aa]);
        float v = fmaxf(D * D - ca * ca, 0.0f);
        atomicMax(&Ms[bcol], __float_as_uint(v));
    }
    __syncthreads();
    // --- keys ---
    for (int b = tid; b < m; b += 256) {
        float sc = Sc[b];
        float key = (sc * __expf(-2.0f * __uint_as_float(Ms[b])) >= 0.5f) ? sc : -1.0f;
        keys[mem[b]] = key;
    }
}

// ---------------- Kernel 3: bitonic top-k + small outputs ----------------
__global__ __launch_bounds__(1024) void sortk_kernel(
        const float* __restrict__ keys, const float* __restrict__ scores,
        const int* __restrict__ labels, const float* __restrict__ factors,
        int* __restrict__ sel, float* __restrict__ out_small) {
    __shared__ u64 k2[KEYPAD];
    const int tid = threadIdx.x;
    for (int i = tid; i < KEYPAD; i += 1024) {
        u64 v = 0;
        if (i < N_MASKS) {
            u32 fb = __float_as_uint(keys[i]);
            u32 od = (fb & 0x80000000u) ? ~fb : (fb | 0x80000000u);  // order-keep
            v = ((u64)od << 32) | (u32)(~(u32)i);                    // tie->low idx
        }
        k2[i] = v;
    }
    __syncthreads();
    for (int k = 2; k <= KEYPAD; k <<= 1) {
        for (int j = k >> 1; j > 0; j >>= 1) {
            for (int i = tid; i < KEYPAD; i += 1024) {
                int p = i ^ j;
                if (p > i) {
                    bool desc = ((i & k) == 0);
                    u64 x = k2[i], y = k2[p];
                    if ((x < y) == desc) { k2[i] = y; k2[p] = x; }
                }
            }
            __syncthreads();
        }
    }
    for (int r = tid; r < POST_NMS_K; r += 1024) {
        u64 v = k2[r];
        u32 od = (u32)(v >> 32);
        bool kept = (od >= 0x80000000u);    // key float >= 0 (pads have od==0)
        int idx = (int)(~(u32)v);
        if (kept) {
            sel[r] = idx;
            out_small[r] = scores[idx];
            out_small[POST_NMS_K + r] = (float)labels[idx];
            out_small[2 * POST_NMS_K + r] = factors[idx];
        } else {
            sel[r] = -1;
            out_small[r] = 0.0f;
            out_small[POST_NMS_K + r] = -1.0f;
            out_small[2 * POST_NMS_K + r] = 0.0f;
        }
    }
}

// ---------------- Kernel 4: gather seg rows ----------------
__global__ __launch_bounds__(256) void gather_kernel(const float4* __restrict__ seg,
                                                     const int* __restrict__ sel,
                                                     float4* __restrict__ out) {
    int row = blockIdx.y;
    int col = blockIdx.x * blockDim.x + threadIdx.x;   // 0..12543
    int s = sel[row];
    float4 v = make_float4(0.f, 0.f, 0.f, 0.f);
    if (s >= 0) v = seg[(size_t)s * (HW / 4) + col];
    out[(size_t)row * (HW / 4) + col] = v;
}

extern "C" void kernel_launch(void* const* d_in, const int* in_sizes, int n_in,
                              void* d_out, int out_size, void* d_ws, size_t ws_size,
                              hipStream_t stream) {
    const int* labels = (const int*)d_in[0];
    const float* scores = (const float*)d_in[1];
    const float* factors = (const float*)d_in[2];
    const float* seg = (const float*)d_in[3];
    const float* masks = (const float*)d_in[4];
    const float* msum = (const float*)d_in[5];

    float* out = (float*)d_out;
    // bits scratch in d_out's seg region (fully overwritten by gather at end)
    u64* bits = (u64*)d_out;

    // d_ws: keys[1536] sel[768]
    float* keys = (float*)d_ws;
    int* sel = (int*)(keys + N_MASKS);

    {   // pack: 1536 masks * 196 wave-groups of 256 px; 4 waves/block
        int groups = N_MASKS * (HW / 256);
        pack_kernel<<<groups / 4, 256, 0, stream>>>((const float4*)masks, bits);
    }
    classnms_kernel<<<NCLS, 256, 0, stream>>>(labels, scores, msum, bits, keys);
    sortk_kernel<<<1, 1024, 0, stream>>>(keys, scores, labels, factors, sel,
                                         out + SEG_ELEMS);
    {   // gather: 12544 float4 per row; 49 blocks x 256 threads
        dim3 grid(49, POST_NMS_K);
        gather_kernel<<<grid, 256, 0, stream>>>((const float4*)seg, sel,
                                                (float4*)out);
    }
}

// Round 6
// 199.592 us; speedup vs baseline: 1.5047x; 1.0128x over previous
//
#include <hip/hip_runtime.h>
#include <stdint.h>

typedef unsigned long long u64;
typedef unsigned int u32;
typedef unsigned short u16;

#define N_MASKS 1536
#define HW 50176           // 224*224
#define WORDS 784
#define NCLS 80
#define POST_NMS_K 768
#define SEG_ELEMS ((size_t)POST_NMS_K * HW)   // 38,535,168
#define KEYPAD 2048

#define MMAX 96                       // max members/class (R5 verified m<=96)
#define MAXPAIRS (MMAX*(MMAX-1)/2)    // 4560
#define TW 112                        // u64 words per LDS tile; 784 = 7*112
#define TWP 113                       // padded stride: 4-way-max bank spread
#define NTILES (WORDS/TW)             // 7
#define CT 512                        // classnms threads

// ---------------- Kernel 1: bitpack via wave ballot, 4KB/wave ----------------
// Wave handles 1024 px as 4 groups of 256: 4 float4 loads/lane issued together,
// 16 ballots, lanes 0..3 store 4 words each (128B contiguous per wave).
// Fixed pixel->bit permutation, identical across masks: popcount(a&b) exact.
__global__ __launch_bounds__(256) void pack_kernel(const float4* __restrict__ masks,
                                                   u64* __restrict__ bits) {
    int gid = blockIdx.x * blockDim.x + threadIdx.x;
    int wave = gid >> 6;                 // covers pixels [wave*1024, wave*1024+1024)
    int lane = gid & 63;
    float4 v[4];
#pragma unroll
    for (int g = 0; g < 4; ++g)
        v[g] = masks[(size_t)wave * 256 + g * 64 + lane];
    u64 w[16];
#pragma unroll
    for (int g = 0; g < 4; ++g) {
        w[g * 4 + 0] = __ballot(v[g].x > 0.5f);
        w[g * 4 + 1] = __ballot(v[g].y > 0.5f);
        w[g * 4 + 2] = __ballot(v[g].z > 0.5f);
        w[g * 4 + 3] = __ballot(v[g].w > 0.5f);
    }
    if (lane < 4) {
#pragma unroll
        for (int g = 0; g < 4; ++g)
            bits[(size_t)wave * 16 + g * 4 + lane] = w[g * 4 + lane];
    }
}

// ---------------- Kernel 2: fused per-class matrix NMS (512 thr) -----------
// D[a][b] = I/(2*S_b - I + eps)   (reference quirk: union = 2*S_col - I)
// M[b] = max(0, max_{a<b}(D^2 - comp[a]^2)); key = (sc*exp(-2M) >= 0.5)?sc:-1
__global__ __launch_bounds__(CT) void classnms_kernel(
        const int* __restrict__ labels, const float* __restrict__ scores,
        const float* __restrict__ msum, const u64* __restrict__ bits,
        float* __restrict__ keys) {
    const int cls = blockIdx.x;
    const int tid = threadIdx.x;
    __shared__ int mem[MMAX];
    __shared__ float Sm[MMAX], Sc[MMAX];
    __shared__ u32 compS[MMAX], Ms[MMAX];
    __shared__ u16 lutAB[MAXPAIRS];          // (a<<8)|b
    __shared__ u32 Ipair[MAXPAIRS];          // intersections, then D bits
    __shared__ u64 rows[MMAX * TWP];         // 96*113*8 = 86.6 KB
    __shared__ int scan[CT];
    __shared__ int mtot;

    // --- ordered compaction: thread t owns indices [3t, 3t+3) ---
    const int PER = N_MASKS / CT;            // 3
    int lab[PER]; int cnt = 0;
#pragma unroll
    for (int k = 0; k < PER; ++k) { lab[k] = labels[tid * PER + k]; cnt += (lab[k] == cls); }
    scan[tid] = cnt;
    __syncthreads();
    for (int off = 1; off < CT; off <<= 1) {    // Hillis-Steele inclusive scan
        int vv = scan[tid];
        int uu = (tid >= off) ? scan[tid - off] : 0;
        __syncthreads();
        scan[tid] = vv + uu;
        __syncthreads();
    }
    {
        int o = scan[tid] - cnt;             // exclusive offset
#pragma unroll
        for (int k = 0; k < PER; ++k)
            if (lab[k] == cls) mem[o++] = tid * PER + k;
    }
    if (tid == CT - 1) mtot = scan[CT - 1];
    __syncthreads();
    const int m = mtot;
    const int np = m * (m - 1) / 2;

    for (int b = tid; b < m; b += CT) {
        int g = mem[b];
        Sm[b] = msum[g]; Sc[b] = scores[g];
        compS[b] = 0u; Ms[b] = 0u;
    }
    for (int p = tid; p < np; p += CT) {     // pair LUT (decode once)
        int bb = (int)((1.0 + sqrt(1.0 + 8.0 * (double)p)) * 0.5);
        while (bb * (bb - 1) / 2 > p) --bb;
        while ((bb + 1) * bb / 2 <= p) ++bb;
        int aa = p - bb * (bb - 1) / 2;
        lutAB[p] = (u16)((aa << 8) | bb);
        Ipair[p] = 0u;
    }

    // --- tiled pairwise popcount from LDS ---
    const int nb = m * (TW / 2);             // 16B blocks to stage per tile
    for (int t = 0; t < NTILES; ++t) {
        __syncthreads();
        // stage: 4-wide ILP of predicated 16B global loads, then LDS writes
        for (int base = 0; base < nb; base += 4 * CT) {
            ulonglong2 vv[4]; int dst[4]; bool ok[4];
#pragma unroll
            for (int u = 0; u < 4; ++u) {
                int blk = base + u * CT + tid;
                ok[u] = (blk < nb);
                if (ok[u]) {
                    int r = blk / (TW / 2), k = blk - r * (TW / 2);
                    dst[u] = r * TWP + 2 * k;
                    vv[u] = *(const ulonglong2*)(bits + (size_t)mem[r] * WORDS
                                                 + t * TW + 2 * k);
                }
            }
#pragma unroll
            for (int u = 0; u < 4; ++u)
                if (ok[u]) { rows[dst[u]] = vv[u].x; rows[dst[u] + 1] = vv[u].y; }
        }
        __syncthreads();
        for (int p = tid; p < np; p += CT) {
            int ab = lutAB[p];
            const u64* ra = &rows[(ab >> 8) * TWP];
            const u64* rb = &rows[(ab & 255) * TWP];
            u32 s = 0;
#pragma unroll 8
            for (int w = 0; w < TW; ++w) s += (u32)__popcll(ra[w] & rb[w]);
            Ipair[p] += s;                   // thread owns p: plain add
        }
    }
    __syncthreads();

    // --- D + compensate ---
    for (int p = tid; p < np; p += CT) {
        int ab = lutAB[p]; int bcol = ab & 255;
        float fI = (float)Ipair[p];
        float D = fI / (2.0f * Sm[bcol] - fI + 1e-6f);   // D in [0,1]
        Ipair[p] = __float_as_uint(D);       // same-thread overwrite: safe
        atomicMax(&compS[bcol], __float_as_uint(D));     // non-neg: uint==float order
    }
    __syncthreads();
    // --- M ---
    for (int p = tid; p < np; p += CT) {
        int ab = lutAB[p]; int aa = ab >> 8; int bcol = ab & 255;
        float D = __uint_as_float(Ipair[p]);
        float ca = __uint_as_float(compS[aa]);
        float v = fmaxf(D * D - ca * ca, 0.0f);
        atomicMax(&Ms[bcol], __float_as_uint(v));
    }
    __syncthreads();
    // --- keys ---
    for (int b = tid; b < m; b += CT) {
        float sc = Sc[b];
        float key = (sc * __expf(-2.0f * __uint_as_float(Ms[b])) >= 0.5f) ? sc : -1.0f;
        keys[mem[b]] = key;
    }
}

// ---------------- Kernel 3: bitonic top-k + small outputs ----------------
__global__ __launch_bounds__(1024) void sortk_kernel(
        const float* __restrict__ keys, const float* __restrict__ scores,
        const int* __restrict__ labels, const float* __restrict__ factors,
        int* __restrict__ sel, float* __restrict__ out_small) {
    __shared__ u64 k2[KEYPAD];
    const int tid = threadIdx.x;
    for (int i = tid; i < KEYPAD; i += 1024) {
        u64 v = 0;
        if (i < N_MASKS) {
            u32 fb = __float_as_uint(keys[i]);
            u32 od = (fb & 0x80000000u) ? ~fb : (fb | 0x80000000u);  // order-keep
            v = ((u64)od << 32) | (u32)(~(u32)i);                    // tie->low idx
        }
        k2[i] = v;
    }
    __syncthreads();
    for (int k = 2; k <= KEYPAD; k <<= 1) {
        for (int j = k >> 1; j > 0; j >>= 1) {
            for (int i = tid; i < KEYPAD; i += 1024) {
                int p = i ^ j;
                if (p > i) {
                    bool desc = ((i & k) == 0);
                    u64 x = k2[i], y = k2[p];
                    if ((x < y) == desc) { k2[i] = y; k2[p] = x; }
                }
            }
            __syncthreads();
        }
    }
    for (int r = tid; r < POST_NMS_K; r += 1024) {
        u64 v = k2[r];
        u32 od = (u32)(v >> 32);
        bool kept = (od >= 0x80000000u);    // key float >= 0 (pads have od==0)
        int idx = (int)(~(u32)v);
        if (kept) {
            sel[r] = idx;
            out_small[r] = scores[idx];
            out_small[POST_NMS_K + r] = (float)labels[idx];
            out_small[2 * POST_NMS_K + r] = factors[idx];
        } else {
            sel[r] = -1;
            out_small[r] = 0.0f;
            out_small[POST_NMS_K + r] = -1.0f;
            out_small[2 * POST_NMS_K + r] = 0.0f;
        }
    }
}

// ---------------- Kernel 4: gather seg rows, 64B/thread ----------------
__global__ __launch_bounds__(256) void gather_kernel(const float4* __restrict__ seg,
                                                     const int* __restrict__ sel,
                                                     float4* __restrict__ out) {
    const int row = blockIdx.y;
    const int s = sel[row];
    const size_t ob = (size_t)row * (HW / 4);
    const size_t ib = (s >= 0) ? (size_t)s * (HW / 4) : 0;
    const float4 z = make_float4(0.f, 0.f, 0.f, 0.f);
#pragma unroll
    for (int u = 0; u < 4; ++u) {
        int col = blockIdx.x * 1024 + u * 256 + threadIdx.x;
        if (col < HW / 4)
            out[ob + col] = (s >= 0) ? seg[ib + col] : z;
    }
}

extern "C" void kernel_launch(void* const* d_in, const int* in_sizes, int n_in,
                              void* d_out, int out_size, void* d_ws, size_t ws_size,
                              hipStream_t stream) {
    const int* labels = (const int*)d_in[0];
    const float* scores = (const float*)d_in[1];
    const float* factors = (const float*)d_in[2];
    const float* seg = (const float*)d_in[3];
    const float* masks = (const float*)d_in[4];
    const float* msum = (const float*)d_in[5];

    float* out = (float*)d_out;
    // bits scratch in d_out's seg region (fully overwritten by gather at end)
    u64* bits = (u64*)d_out;

    // d_ws: keys[1536] sel[768]
    float* keys = (float*)d_ws;
    int* sel = (int*)(keys + N_MASKS);

    {   // pack: 1536 masks * 49 wave-groups of 1024 px; 4 waves/block
        int waves = N_MASKS * (HW / 1024);          // 75264
        pack_kernel<<<waves / 4, 256, 0, stream>>>((const float4*)masks, bits);
    }
    classnms_kernel<<<NCLS, CT, 0, stream>>>(labels, scores, msum, bits, keys);
    sortk_kernel<<<1, 1024, 0, stream>>>(keys, scores, labels, factors, sel,
                                         out + SEG_ELEMS);
    {   // gather: 12544 float4 per row; 13 blocks x 256 threads x 4 f4
        dim3 grid(13, POST_NMS_K);
        gather_kernel<<<grid, 256, 0, stream>>>((const float4*)seg, sel,
                                                (float4*)out);
    }
}